// Round 3
// baseline (1094.693 us; speedup 1.0000x reference)
//
#include <hip/hip_runtime.h>

#define NB 8
#define NN 2048
#define MM 2048
#define DD 64
#define NCHK 16
#define TS 128
#define L2E 1.4426950408889634f
#define LN2 0.6931471805599453f

typedef _Float16 half_t;
typedef __attribute__((ext_vector_type(8))) _Float16 f16x8;
typedef __attribute__((ext_vector_type(4))) float f32x4;

// ---------------------------------------------------------------------------
// Static device scratch. C is never materialized: dot products are computed
// TWICE by MFMA (pass 1: maxes, pass 2: exp2 sums) so no 64-reg accumulator
// stays live -> ~half the register pressure -> 2x occupancy. MFMA is ~6% util
// so the recompute is nearly free.
// ---------------------------------------------------------------------------
__device__ half_t g_xh[NB * NN * DD];           // fp16 copies for MFMA
__device__ half_t g_yh[NB * MM * DD];
__device__ float g_fab[3][NB * NN], g_gba[3][NB * NN];
__device__ float g_faa[3][NB * NN], g_gbb[3][NB * NN];
__device__ float g_alog[NB * NN], g_blog[NB * NN];   // log2(w)
__device__ float g_xn[NB * NN], g_yn[NB * NN];       // 0.5*||row||^2 (natural)
__device__ float g_h0[NB * MM], g_h1[NB * NN], g_h2[NB * NN], g_h3[NB * MM];
// chunked softmin partials (m,s) in log2 domain: [b][chunk][row]
__device__ float2 g_pfab[NB * NCHK * NN];
__device__ float2 g_pgba[NB * NCHK * NN];
__device__ float2 g_pfaa[NB * NCHK * NN];
__device__ float2 g_pgbb[NB * NCHK * NN];

// ---------------------------------------------------------------------------
__global__ __launch_bounds__(256) void prep_kernel(
    const float* __restrict__ x, const float* __restrict__ y,
    const float* __restrict__ w1, const float* __restrict__ w2)
{
  int gid = blockIdx.x * 256 + threadIdx.x;
  if (gid < NB * NN) {
    g_alog[gid] = log2f(w1[gid]);
    g_blog[gid] = log2f(w2[gid]);
  }
  int lane = threadIdx.x & 63;
  int row = blockIdx.x * 4 + (threadIdx.x >> 6);   // grid 4096 -> rows 0..16383
  float xv = x[(size_t)row * DD + lane];
  float yv = y[(size_t)row * DD + lane];
  g_xh[(size_t)row * DD + lane] = (half_t)xv;
  g_yh[(size_t)row * DD + lane] = (half_t)yv;
  float sx = xv * xv;
  float sy = yv * yv;
#pragma unroll
  for (int off = 32; off > 0; off >>= 1) {
    sx += __shfl_down(sx, off);
    sy += __shfl_down(sy, off);
  }
  if (lane == 0) {
    g_xn[row] = 0.5f * sx;
    g_yn[row] = 0.5f * sy;
  }
}

// ---------------------------------------------------------------------------
__global__ __launch_bounds__(256) void hprep_kernel(
    const float* __restrict__ fab_in, const float* __restrict__ gba_in,
    const float* __restrict__ faa_in, const float* __restrict__ gbb_in,
    float gs2)
{
  int i = blockIdx.x * 256 + threadIdx.x;   // grid 64 -> 16384
  g_h0[i] = fmaf(gs2, gba_in[i], g_blog[i]);
  g_h1[i] = fmaf(gs2, fab_in[i], g_alog[i]);
  g_h2[i] = fmaf(gs2, faa_in[i], g_alog[i]);
  g_h3[i] = fmaf(gs2, gbb_in[i], g_blog[i]);
}

// ---------------------------------------------------------------------------
// Fused cost-recompute + tile-partial softmin, two-pass / low-VGPR variant.
// 128x128 tile per 256-thread block. LDS-staged A/B (XOR-swizzled source,
// linear dest, swizzled ds_read). Row reductions via 16-lane shfl_xor
// butterflies (partials live in 16 contiguous lanes); col reductions via
// in-wave quad shfl + tiny [128][4] LDS merge. 3 barriers total.
// ---------------------------------------------------------------------------
struct FusedArgs {
  const half_t* Af;     // fragment rows (x or y)
  const half_t* Bf;     // fragment cols
  const float* nrow;    // xn or yn for rows
  const float* ncol;    // for cols
  const float* hrow;    // h over cols (row direction softmin), log2 dom.
  const float* hcol;    // h over rows
  float2* prow;         // [b][chunk][row]
  float2* pcol;
  int sym;              // 1 => diagonal col-dir partial is skipped
};

__global__ __launch_bounds__(256, 4) void tile_fused(
    FusedArgs T0, FusedArgs T1, FusedArgs T2, float keps)   // keps = log2e/eps
{
  // flattened grid: 2048 xy tiles + 2*1088 triangular tiles = 4224 blocks
  int u = blockIdx.x;
  int slab, b, I, J;
  if (u < 2048) {
    slab = 0; b = u >> 8;
    int tt = u & 255; I = tt >> 4; J = tt & 15;
  } else {
    int v = u - 2048;
    slab = 1 + v / 1088;
    int w2 = v % 1088;
    b = w2 / 136;
    int rem = w2 % 136, ii = 0;
    while (rem >= NCHK - ii) { rem -= NCHK - ii; ++ii; }   // uniform, <=16 iters
    I = ii; J = ii + rem;                                  // I <= J
  }
  FusedArgs A = (slab == 0) ? T0 : (slab == 1) ? T1 : T2;

  const int t = threadIdx.x;
  const int w = t >> 6, lane = t & 63;
  const int m = lane & 15, quad = lane >> 4;
  const int i0 = I * TS, j0 = J * TS;

  __shared__ __align__(16) char stage[2 * TS * DD * 2];   // 32 KB (A | B)
  __shared__ __align__(16) float cmaxw[TS][4];            // per-wave col maxes
  __shared__ __align__(16) float csumw[TS][4];            // per-wave col sums

  // ---- stage A (16 KB) + B (16 KB) into LDS via global_load_lds ----
  // Linear LDS layout [row][128B]; source column XOR-swizzled by (row&7)<<4.
  {
    const char* gA = (const char*)(A.Af + ((size_t)b * NN + i0) * DD);
    const char* gB = (const char*)(A.Bf + ((size_t)b * MM + j0) * DD);
#pragma unroll
    for (int k = 0; k < 8; ++k) {
      int seg = w * 8 + k;                       // wave-uniform
      int p = (seg * 1024 + lane * 16) & 16383;  // byte pos within buffer
      int row = p >> 7, colb = p & 127;
      int colx = colb ^ ((row & 7) << 4);
      const char* src = (seg < 16 ? gA : gB) + (size_t)row * 128 + colx;
      __builtin_amdgcn_global_load_lds(
          (const __attribute__((address_space(1))) unsigned int*)src,
          (__attribute__((address_space(3))) unsigned int*)(stage + seg * 1024),
          16, 0, 0);
    }
  }

  // ---- per-thread row/col scalars (overlap with staging DMA) ----
  float4 xr[2], hq[2];
#pragma unroll
  for (int g = 0; g < 2; ++g) {
    size_t ro = (size_t)b * NN + i0 + 32 * w + 16 * g + 4 * quad;
    xr[g] = *(const float4*)(A.nrow + ro);
    hq[g] = *(const float4*)(A.hcol + ro);
  }
  float ynk[8], hr[8];
#pragma unroll
  for (int c = 0; c < 8; ++c) {
    size_t co = (size_t)b * MM + j0 + 16 * c + m;
    ynk[c] = -A.ncol[co] * keps;
    hr[c] = A.hrow[co];
  }
  float xnk[2][4], hcv[2][4];
#pragma unroll
  for (int g = 0; g < 2; ++g) {
    xnk[g][0] = -xr[g].x * keps; xnk[g][1] = -xr[g].y * keps;
    xnk[g][2] = -xr[g].z * keps; xnk[g][3] = -xr[g].w * keps;
    hcv[g][0] = hq[g].x; hcv[g][1] = hq[g].y;
    hcv[g][2] = hq[g].z; hcv[g][3] = hq[g].w;
  }

  __syncthreads();   // staging complete

  // ---- A fragments, resident across both passes (16 VGPR) ----
  const int qb0 = quad * 16, qb1 = quad * 16 + 64;
  const int ra0 = 32 * w + m, ra1 = 32 * w + 16 + m;
  const int sa0 = (ra0 & 7) << 4, sa1 = (ra1 & 7) << 4;
  f16x8 a00 = *(const f16x8*)(stage + ra0 * 128 + (qb0 ^ sa0));
  f16x8 a01 = *(const f16x8*)(stage + ra0 * 128 + (qb1 ^ sa0));
  f16x8 a10 = *(const f16x8*)(stage + ra1 * 128 + (qb0 ^ sa1));
  f16x8 a11 = *(const f16x8*)(stage + ra1 * 128 + (qb1 ^ sa1));

  // ---- pass 1: maxes (acc regs re-used per c-group: only 8 live) ----
  float rm[2][4], cm8[8];
#pragma unroll
  for (int g = 0; g < 2; ++g)
#pragma unroll
    for (int r = 0; r < 4; ++r) rm[g][r] = -3.0e38f;

#pragma unroll
  for (int c = 0; c < 8; ++c) {
    const int rb = 16 * c + m, sw = (rb & 7) << 4;
    const char* bp = stage + 16384 + rb * 128;
    f16x8 b0 = *(const f16x8*)(bp + (qb0 ^ sw));
    f16x8 b1 = *(const f16x8*)(bp + (qb1 ^ sw));
    f32x4 acc0 = {0.f, 0.f, 0.f, 0.f}, acc1 = {0.f, 0.f, 0.f, 0.f};
    acc0 = __builtin_amdgcn_mfma_f32_16x16x32_f16(a00, b0, acc0, 0, 0, 0);
    acc0 = __builtin_amdgcn_mfma_f32_16x16x32_f16(a01, b1, acc0, 0, 0, 0);
    acc1 = __builtin_amdgcn_mfma_f32_16x16x32_f16(a10, b0, acc1, 0, 0, 0);
    acc1 = __builtin_amdgcn_mfma_f32_16x16x32_f16(a11, b1, acc1, 0, 0, 0);
    float cmc = -3.0e38f;
#pragma unroll
    for (int g = 0; g < 2; ++g) {
      f32x4 v = g ? acc1 : acc0;
#pragma unroll
      for (int r = 0; r < 4; ++r) {
        float bse = fminf(fmaf(v[r], keps, xnk[g][r]) + ynk[c], 0.f);
        rm[g][r] = fmaxf(rm[g][r], bse + hr[c]);
        cmc = fmaxf(cmc, bse + hcv[g][r]);
      }
    }
    cm8[c] = cmc;
  }

  // row maxes: butterfly over the 16 lanes of the quad-group (no barrier)
  float rmv[2][4];
#pragma unroll
  for (int g = 0; g < 2; ++g)
#pragma unroll
    for (int r = 0; r < 4; ++r) {
      float v = rm[g][r];
      v = fmaxf(v, __shfl_xor(v, 1));
      v = fmaxf(v, __shfl_xor(v, 2));
      v = fmaxf(v, __shfl_xor(v, 4));
      v = fmaxf(v, __shfl_xor(v, 8));
      rmv[g][r] = v;
    }

  // col maxes: quad-reduce in-wave, then 4-wave merge through LDS
#pragma unroll
  for (int c = 0; c < 8; ++c) {
    float v = cm8[c];
    v = fmaxf(v, __shfl_xor(v, 16));
    v = fmaxf(v, __shfl_xor(v, 32));
    cm8[c] = v;
  }
  if (quad == 0) {
#pragma unroll
    for (int c = 0; c < 8; ++c) cmaxw[16 * c + m][w] = cm8[c];
  }
  __syncthreads();
  float cmv[8];
#pragma unroll
  for (int c = 0; c < 8; ++c) {
    float4 q4 = *(const float4*)cmaxw[16 * c + m];
    cmv[c] = fmaxf(fmaxf(q4.x, q4.y), fmaxf(q4.z, q4.w));
  }

  // ---- pass 2: recompute dots, accumulate exp2 sums ----
  float rs[2][4], cs8[8];
#pragma unroll
  for (int g = 0; g < 2; ++g)
#pragma unroll
    for (int r = 0; r < 4; ++r) rs[g][r] = 0.f;

#pragma unroll
  for (int c = 0; c < 8; ++c) {
    const int rb = 16 * c + m, sw = (rb & 7) << 4;
    const char* bp = stage + 16384 + rb * 128;
    f16x8 b0 = *(const f16x8*)(bp + (qb0 ^ sw));
    f16x8 b1 = *(const f16x8*)(bp + (qb1 ^ sw));
    f32x4 acc0 = {0.f, 0.f, 0.f, 0.f}, acc1 = {0.f, 0.f, 0.f, 0.f};
    acc0 = __builtin_amdgcn_mfma_f32_16x16x32_f16(a00, b0, acc0, 0, 0, 0);
    acc0 = __builtin_amdgcn_mfma_f32_16x16x32_f16(a01, b1, acc0, 0, 0, 0);
    acc1 = __builtin_amdgcn_mfma_f32_16x16x32_f16(a10, b0, acc1, 0, 0, 0);
    acc1 = __builtin_amdgcn_mfma_f32_16x16x32_f16(a11, b1, acc1, 0, 0, 0);
    float csc = 0.f;
#pragma unroll
    for (int g = 0; g < 2; ++g) {
      f32x4 v = g ? acc1 : acc0;
#pragma unroll
      for (int r = 0; r < 4; ++r) {
        float bse = fminf(fmaf(v[r], keps, xnk[g][r]) + ynk[c], 0.f);
        rs[g][r] += __builtin_amdgcn_exp2f(bse + hr[c] - rmv[g][r]);
        csc += __builtin_amdgcn_exp2f(bse + hcv[g][r] - cmv[c]);
      }
    }
    cs8[c] = csc;
  }

  // row sums: butterfly over 16 lanes; lanes m==0 write the row partials
#pragma unroll
  for (int g = 0; g < 2; ++g)
#pragma unroll
    for (int r = 0; r < 4; ++r) {
      float v = rs[g][r];
      v += __shfl_xor(v, 1);
      v += __shfl_xor(v, 2);
      v += __shfl_xor(v, 4);
      v += __shfl_xor(v, 8);
      rs[g][r] = v;
    }
  if (m == 0) {
    float2* pr = A.prow + ((size_t)b * NCHK + J) * NN + i0;
#pragma unroll
    for (int g = 0; g < 2; ++g)
#pragma unroll
      for (int r = 0; r < 4; ++r) {
        int row = 32 * w + 16 * g + 4 * quad + r;
        pr[row] = make_float2(rmv[g][r], rs[g][r]);
      }
  }

  // col sums: quad-reduce in-wave, 4-wave merge, coalesced pcol write
#pragma unroll
  for (int c = 0; c < 8; ++c) {
    float v = cs8[c];
    v += __shfl_xor(v, 16);
    v += __shfl_xor(v, 32);
    cs8[c] = v;
  }
  if (quad == 0) {
#pragma unroll
    for (int c = 0; c < 8; ++c) csumw[16 * c + m][w] = cs8[c];
  }
  __syncthreads();
  if (t < TS && !(A.sym && I == J)) {   // diagonal col-dir duplicates row-dir
    float4 mq = *(const float4*)cmaxw[t];
    float4 sq = *(const float4*)csumw[t];
    float M = fmaxf(fmaxf(mq.x, mq.y), fmaxf(mq.z, mq.w));
    float S = sq.x + sq.y + sq.z + sq.w;
    A.pcol[((size_t)b * NCHK + I) * NN + j0 + t] = make_float2(M, S);
  }
}

// ---------------------------------------------------------------------------
// merge 16 chunk-partials per row -> softmin + Jacobi update + next-h write.
// Partials in log2 domain: ft = -eps*ln2*(M + log2(S)).
// ---------------------------------------------------------------------------
struct MergeArgs {
  const float2* part;
  const float* fold;
  float* fout;
  const float* hbase;   // alog or blog (log2 domain)
  float* hout;          // h vector consumed by the next tile_fused
};

__global__ __launch_bounds__(256) void merge4(
    MergeArgs M0, MergeArgs M1, MergeArgs M2, MergeArgs M3,
    float eps, float alpha, float beta, float nextgs)
{
  MergeArgs A = (blockIdx.z == 0) ? M0 : (blockIdx.z == 1) ? M1
              : (blockIdx.z == 2) ? M2 : M3;
  const int b = blockIdx.y;
  const int i = blockIdx.x * 256 + threadIdx.x;   // grid.x = NN/256
  float2 p[NCHK];
#pragma unroll
  for (int k = 0; k < NCHK; ++k)
    p[k] = A.part[((size_t)b * NCHK + k) * NN + i];
  float M = p[0].x;
#pragma unroll
  for (int k = 1; k < NCHK; ++k) M = fmaxf(M, p[k].x);
  float S = 0.f;
#pragma unroll
  for (int k = 0; k < NCHK; ++k) S += p[k].y * __builtin_amdgcn_exp2f(p[k].x - M);
  float ft = (-LN2 * eps) * (M + __log2f(S));
  int idx = b * NN + i;
  float fnew = alpha * A.fold[idx] + beta * ft;
  A.fout[idx] = fnew;
  A.hout[idx] = fmaf(nextgs * L2E, fnew, A.hbase[idx]);
}

// ---------------------------------------------------------------------------
__global__ __launch_bounds__(256) void loss_kernel(
    const float* __restrict__ w1, const float* __restrict__ w2,
    float* __restrict__ out)
{
  __shared__ float red[256];
  float acc = 0.f;
  for (int idx = threadIdx.x; idx < NB * NN; idx += 256) {
    acc += w1[idx] * (g_fab[2][idx] - g_faa[2][idx])
         + w2[idx] * (g_gba[2][idx] - g_gbb[2][idx]);
  }
  red[threadIdx.x] = acc;
  __syncthreads();
  for (int s = 128; s > 0; s >>= 1) {
    if (threadIdx.x < s) red[threadIdx.x] += red[threadIdx.x + s];
    __syncthreads();
  }
  if (threadIdx.x == 0) out[0] = red[0] * (1.0f / NB);
}

// ---------------------------------------------------------------------------
extern "C" void kernel_launch(void* const* d_in, const int* in_sizes, int n_in,
                              void* d_out, int out_size, void* d_ws, size_t ws_size,
                              hipStream_t stream)
{
  const float* x = (const float*)d_in[0];
  const float* y = (const float*)d_in[1];
  const float* w1 = (const float*)d_in[2];
  const float* w2 = (const float*)d_in[3];
  float* out = (float*)d_out;

  half_t *xh, *yh;
  float *xn, *yn;
  float *h0, *h1, *h2, *h3, *fabp, *gbap, *faap, *gbbp, *alog, *blog;
  float2 *pfab, *pgba, *pfaa, *pgbb;
  hipGetSymbolAddress((void**)&xh, HIP_SYMBOL(g_xh));
  hipGetSymbolAddress((void**)&yh, HIP_SYMBOL(g_yh));
  hipGetSymbolAddress((void**)&xn, HIP_SYMBOL(g_xn));
  hipGetSymbolAddress((void**)&yn, HIP_SYMBOL(g_yn));
  hipGetSymbolAddress((void**)&h0, HIP_SYMBOL(g_h0));
  hipGetSymbolAddress((void**)&h1, HIP_SYMBOL(g_h1));
  hipGetSymbolAddress((void**)&h2, HIP_SYMBOL(g_h2));
  hipGetSymbolAddress((void**)&h3, HIP_SYMBOL(g_h3));
  hipGetSymbolAddress((void**)&fabp, HIP_SYMBOL(g_fab));
  hipGetSymbolAddress((void**)&gbap, HIP_SYMBOL(g_gba));
  hipGetSymbolAddress((void**)&faap, HIP_SYMBOL(g_faa));
  hipGetSymbolAddress((void**)&gbbp, HIP_SYMBOL(g_gbb));
  hipGetSymbolAddress((void**)&alog, HIP_SYMBOL(g_alog));
  hipGetSymbolAddress((void**)&blog, HIP_SYMBOL(g_blog));
  hipGetSymbolAddress((void**)&pfab, HIP_SYMBOL(g_pfab));
  hipGetSymbolAddress((void**)&pgba, HIP_SYMBOL(g_pgba));
  hipGetSymbolAddress((void**)&pfaa, HIP_SYMBOL(g_pfaa));
  hipGetSymbolAddress((void**)&pgbb, HIP_SYMBOL(g_pgbb));

  auto fab = [&](int s) { return fabp + (size_t)s * NB * NN; };
  auto gba = [&](int s) { return gbap + (size_t)s * NB * NN; };
  auto faa = [&](int s) { return faap + (size_t)s * NB * NN; };
  auto gbb = [&](int s) { return gbbp + (size_t)s * NB * NN; };

  // eps schedule (matches the Python double loop, then cast to fp32)
  float eps_list[32];
  int ne = 0;
  {
    double v = 64.0 * 64.0;
    double tgt = 0.05 * 0.05;
    while (v > tgt) { eps_list[ne++] = (float)v; v *= 0.25; }
    eps_list[ne++] = (float)tgt;   // ne == 12
  }

  prep_kernel<<<4096, 256, 0, stream>>>(x, y, w1, w2);

  dim3 tg(4224);                // flattened: 2048 xy + 1088 xx + 1088 yy
  dim3 mg(NN / 256, NB, 4);     // z: potential

  auto launch_iter = [&](float eps, float alpha, float beta, float nextgs,
                         int in, int outsel) {
    float keps = L2E / eps;
    FusedArgs T0 = {xh, yh, xn, yn, h0, h1, pfab, pgba, 0};
    FusedArgs T1 = {xh, xh, xn, xn, h2, h2, pfaa, pfaa, 1};
    FusedArgs T2 = {yh, yh, yn, yn, h3, h3, pgbb, pgbb, 1};
    tile_fused<<<tg, 256, 0, stream>>>(T0, T1, T2, keps);
    MergeArgs M0 = {pfab, fab(in), fab(outsel), alog, h1};
    MergeArgs M1 = {pgba, gba(in), gba(outsel), blog, h0};
    MergeArgs M2 = {pfaa, faa(in), faa(outsel), alog, h2};
    MergeArgs M3 = {pgbb, gbb(in), gbb(outsel), blog, h3};
    merge4<<<mg, 256, 0, stream>>>(M0, M1, M2, M3, eps, alpha, beta, nextgs);
  };

  // init at eps0: h = base log2-weights (gs=0), alpha=0 -> no carry read;
  // its merge writes h for scan step k=0.
  hprep_kernel<<<64, 256, 0, stream>>>(fab(0), gba(0), faa(0), gbb(0), 0.f);
  launch_iter(eps_list[0], 0.f, 1.f, 1.0f / eps_list[0], 0, 0);

  // scan over the full eps list with 0.5-averaging (Jacobi, banks 0/1);
  // each merge writes h for the NEXT step (k+1, or the final extrapolation).
  int cur = 0;
  for (int k = 0; k < ne; ++k) {
    int nxt = 1 - cur;
    float nextgs = 1.0f / ((k < ne - 1) ? eps_list[k + 1] : eps_list[ne - 1]);
    launch_iter(eps_list[k], 0.5f, 0.5f, nextgs, cur, nxt);
    cur = nxt;
  }

  // final extrapolation at eps = blur^p (no averaging) -> bank 2
  launch_iter(eps_list[ne - 1], 0.f, 1.f, 0.f, cur, 2);

  loss_kernel<<<1, 256, 0, stream>>>(w1, w2, out);
}

// Round 4
// 861.145 us; speedup vs baseline: 1.2712x; 1.2712x over previous
//
#include <hip/hip_runtime.h>

#define NB 8
#define NN 2048
#define MM 2048
#define DD 64
#define NCHK 16
#define TS 128
#define L2E 1.4426950408889634f
#define LN2 0.6931471805599453f

typedef _Float16 half_t;
typedef __attribute__((ext_vector_type(8))) _Float16 f16x8;
typedef __attribute__((ext_vector_type(4))) float f32x4;

// ---------------------------------------------------------------------------
// Static device scratch. C is never materialized: dot products are computed
// TWICE by MFMA (pass 1: maxes, pass 2: exp2 sums) so no 64-reg accumulator
// stays live. NOTE: launch_bounds min-waves clamp removed — round-3 showed
// (256,4) forces a 64-VGPR cap and catastrophic scratch spills (WRITE_SIZE
// 8MB -> 162MB). Let the allocator land naturally (~120 VGPR, 4 waves/SIMD).
// ---------------------------------------------------------------------------
__device__ half_t g_xh[NB * NN * DD];           // fp16 copies for MFMA
__device__ half_t g_yh[NB * MM * DD];
__device__ float g_fab[3][NB * NN], g_gba[3][NB * NN];
__device__ float g_faa[3][NB * NN], g_gbb[3][NB * NN];
__device__ float g_alog[NB * NN], g_blog[NB * NN];   // log2(w)
__device__ float g_xn[NB * NN], g_yn[NB * NN];       // 0.5*||row||^2 (natural)
__device__ float g_h0[NB * MM], g_h1[NB * NN], g_h2[NB * NN], g_h3[NB * MM];
// chunked softmin partials (m,s) in log2 domain: [b][chunk][row]
__device__ float2 g_pfab[NB * NCHK * NN];
__device__ float2 g_pgba[NB * NCHK * NN];
__device__ float2 g_pfaa[NB * NCHK * NN];
__device__ float2 g_pgbb[NB * NCHK * NN];

// ---------------------------------------------------------------------------
__global__ __launch_bounds__(256) void prep_kernel(
    const float* __restrict__ x, const float* __restrict__ y,
    const float* __restrict__ w1, const float* __restrict__ w2)
{
  int gid = blockIdx.x * 256 + threadIdx.x;
  if (gid < NB * NN) {
    g_alog[gid] = log2f(w1[gid]);
    g_blog[gid] = log2f(w2[gid]);
  }
  int lane = threadIdx.x & 63;
  int row = blockIdx.x * 4 + (threadIdx.x >> 6);   // grid 4096 -> rows 0..16383
  float xv = x[(size_t)row * DD + lane];
  float yv = y[(size_t)row * DD + lane];
  g_xh[(size_t)row * DD + lane] = (half_t)xv;
  g_yh[(size_t)row * DD + lane] = (half_t)yv;
  float sx = xv * xv;
  float sy = yv * yv;
#pragma unroll
  for (int off = 32; off > 0; off >>= 1) {
    sx += __shfl_down(sx, off);
    sy += __shfl_down(sy, off);
  }
  if (lane == 0) {
    g_xn[row] = 0.5f * sx;
    g_yn[row] = 0.5f * sy;
  }
}

// ---------------------------------------------------------------------------
__global__ __launch_bounds__(256) void hprep_kernel(
    const float* __restrict__ fab_in, const float* __restrict__ gba_in,
    const float* __restrict__ faa_in, const float* __restrict__ gbb_in,
    float gs2)
{
  int i = blockIdx.x * 256 + threadIdx.x;   // grid 64 -> 16384
  g_h0[i] = fmaf(gs2, gba_in[i], g_blog[i]);
  g_h1[i] = fmaf(gs2, fab_in[i], g_alog[i]);
  g_h2[i] = fmaf(gs2, faa_in[i], g_alog[i]);
  g_h3[i] = fmaf(gs2, gbb_in[i], g_blog[i]);
}

// ---------------------------------------------------------------------------
// Fused cost-recompute + tile-partial softmin, two-pass / low-VGPR variant.
// 128x128 tile per 256-thread block. LDS-staged A/B (XOR-swizzled source,
// linear dest, swizzled ds_read). Row reductions via 16-lane shfl_xor
// butterflies; col reductions via in-wave quad shfl + [128][4] LDS merge.
// ---------------------------------------------------------------------------
struct FusedArgs {
  const half_t* Af;     // fragment rows (x or y)
  const half_t* Bf;     // fragment cols
  const float* nrow;    // xn or yn for rows
  const float* ncol;    // for cols
  const float* hrow;    // h over cols (row direction softmin), log2 dom.
  const float* hcol;    // h over rows
  float2* prow;         // [b][chunk][row]
  float2* pcol;
  int sym;              // 1 => diagonal col-dir partial is skipped
};

__global__ __launch_bounds__(256) void tile_fused(
    FusedArgs T0, FusedArgs T1, FusedArgs T2, float keps)   // keps = log2e/eps
{
  // flattened grid: 2048 xy tiles + 2*1088 triangular tiles = 4224 blocks
  int u = blockIdx.x;
  int slab, b, I, J;
  if (u < 2048) {
    slab = 0; b = u >> 8;
    int tt = u & 255; I = tt >> 4; J = tt & 15;
  } else {
    int v = u - 2048;
    slab = 1 + v / 1088;
    int w2 = v % 1088;
    b = w2 / 136;
    int rem = w2 % 136, ii = 0;
    while (rem >= NCHK - ii) { rem -= NCHK - ii; ++ii; }   // uniform, <=16 iters
    I = ii; J = ii + rem;                                  // I <= J
  }
  FusedArgs A = (slab == 0) ? T0 : (slab == 1) ? T1 : T2;

  const int t = threadIdx.x;
  const int w = t >> 6, lane = t & 63;
  const int m = lane & 15, quad = lane >> 4;
  const int i0 = I * TS, j0 = J * TS;

  __shared__ __align__(16) char stage[2 * TS * DD * 2];   // 32 KB (A | B)
  __shared__ __align__(16) float cmaxw[TS][4];            // per-wave col maxes
  __shared__ __align__(16) float csumw[TS][4];            // per-wave col sums

  // ---- stage A (16 KB) + B (16 KB) into LDS via global_load_lds ----
  // Linear LDS layout [row][128B]; source column XOR-swizzled by (row&7)<<4.
  {
    const char* gA = (const char*)(A.Af + ((size_t)b * NN + i0) * DD);
    const char* gB = (const char*)(A.Bf + ((size_t)b * MM + j0) * DD);
#pragma unroll
    for (int k = 0; k < 8; ++k) {
      int seg = w * 8 + k;                       // wave-uniform
      int p = (seg * 1024 + lane * 16) & 16383;  // byte pos within buffer
      int row = p >> 7, colb = p & 127;
      int colx = colb ^ ((row & 7) << 4);
      const char* src = (seg < 16 ? gA : gB) + (size_t)row * 128 + colx;
      __builtin_amdgcn_global_load_lds(
          (const __attribute__((address_space(1))) unsigned int*)src,
          (__attribute__((address_space(3))) unsigned int*)(stage + seg * 1024),
          16, 0, 0);
    }
  }

  // ---- per-thread row/col scalars (overlap with staging DMA) ----
  float4 xr[2], hq[2];
#pragma unroll
  for (int g = 0; g < 2; ++g) {
    size_t ro = (size_t)b * NN + i0 + 32 * w + 16 * g + 4 * quad;
    xr[g] = *(const float4*)(A.nrow + ro);
    hq[g] = *(const float4*)(A.hcol + ro);
  }
  float ynk[8], hr[8];
#pragma unroll
  for (int c = 0; c < 8; ++c) {
    size_t co = (size_t)b * MM + j0 + 16 * c + m;
    ynk[c] = -A.ncol[co] * keps;
    hr[c] = A.hrow[co];
  }
  float xnk[2][4], hcv[2][4];
#pragma unroll
  for (int g = 0; g < 2; ++g) {
    xnk[g][0] = -xr[g].x * keps; xnk[g][1] = -xr[g].y * keps;
    xnk[g][2] = -xr[g].z * keps; xnk[g][3] = -xr[g].w * keps;
    hcv[g][0] = hq[g].x; hcv[g][1] = hq[g].y;
    hcv[g][2] = hq[g].z; hcv[g][3] = hq[g].w;
  }

  __syncthreads();   // staging complete

  // ---- A fragments, resident across both passes (16 VGPR) ----
  const int qb0 = quad * 16, qb1 = quad * 16 + 64;
  const int ra0 = 32 * w + m, ra1 = 32 * w + 16 + m;
  const int sa0 = (ra0 & 7) << 4, sa1 = (ra1 & 7) << 4;
  f16x8 a00 = *(const f16x8*)(stage + ra0 * 128 + (qb0 ^ sa0));
  f16x8 a01 = *(const f16x8*)(stage + ra0 * 128 + (qb1 ^ sa0));
  f16x8 a10 = *(const f16x8*)(stage + ra1 * 128 + (qb0 ^ sa1));
  f16x8 a11 = *(const f16x8*)(stage + ra1 * 128 + (qb1 ^ sa1));

  // ---- pass 1: maxes (acc regs re-used per c-group: only 8 live) ----
  float rm[2][4], cm8[8];
#pragma unroll
  for (int g = 0; g < 2; ++g)
#pragma unroll
    for (int r = 0; r < 4; ++r) rm[g][r] = -3.0e38f;

#pragma unroll
  for (int c = 0; c < 8; ++c) {
    const int rb = 16 * c + m, sw = (rb & 7) << 4;
    const char* bp = stage + 16384 + rb * 128;
    f16x8 b0 = *(const f16x8*)(bp + (qb0 ^ sw));
    f16x8 b1 = *(const f16x8*)(bp + (qb1 ^ sw));
    f32x4 acc0 = {0.f, 0.f, 0.f, 0.f}, acc1 = {0.f, 0.f, 0.f, 0.f};
    acc0 = __builtin_amdgcn_mfma_f32_16x16x32_f16(a00, b0, acc0, 0, 0, 0);
    acc0 = __builtin_amdgcn_mfma_f32_16x16x32_f16(a01, b1, acc0, 0, 0, 0);
    acc1 = __builtin_amdgcn_mfma_f32_16x16x32_f16(a10, b0, acc1, 0, 0, 0);
    acc1 = __builtin_amdgcn_mfma_f32_16x16x32_f16(a11, b1, acc1, 0, 0, 0);
    float cmc = -3.0e38f;
#pragma unroll
    for (int g = 0; g < 2; ++g) {
      f32x4 v = g ? acc1 : acc0;
#pragma unroll
      for (int r = 0; r < 4; ++r) {
        float bse = fminf(fmaf(v[r], keps, xnk[g][r]) + ynk[c], 0.f);
        rm[g][r] = fmaxf(rm[g][r], bse + hr[c]);
        cmc = fmaxf(cmc, bse + hcv[g][r]);
      }
    }
    cm8[c] = cmc;
  }

  // row maxes: butterfly over the 16 lanes of the quad-group (no barrier)
  float rmv[2][4];
#pragma unroll
  for (int g = 0; g < 2; ++g)
#pragma unroll
    for (int r = 0; r < 4; ++r) {
      float v = rm[g][r];
      v = fmaxf(v, __shfl_xor(v, 1));
      v = fmaxf(v, __shfl_xor(v, 2));
      v = fmaxf(v, __shfl_xor(v, 4));
      v = fmaxf(v, __shfl_xor(v, 8));
      rmv[g][r] = v;
    }

  // col maxes: quad-reduce in-wave, then 4-wave merge through LDS
#pragma unroll
  for (int c = 0; c < 8; ++c) {
    float v = cm8[c];
    v = fmaxf(v, __shfl_xor(v, 16));
    v = fmaxf(v, __shfl_xor(v, 32));
    cm8[c] = v;
  }
  if (quad == 0) {
#pragma unroll
    for (int c = 0; c < 8; ++c) cmaxw[16 * c + m][w] = cm8[c];
  }
  __syncthreads();
  float cmv[8];
#pragma unroll
  for (int c = 0; c < 8; ++c) {
    float4 q4 = *(const float4*)cmaxw[16 * c + m];
    cmv[c] = fmaxf(fmaxf(q4.x, q4.y), fmaxf(q4.z, q4.w));
  }

  // ---- pass 2: recompute dots, accumulate exp2 sums ----
  float rs[2][4], cs8[8];
#pragma unroll
  for (int g = 0; g < 2; ++g)
#pragma unroll
    for (int r = 0; r < 4; ++r) rs[g][r] = 0.f;

#pragma unroll
  for (int c = 0; c < 8; ++c) {
    const int rb = 16 * c + m, sw = (rb & 7) << 4;
    const char* bp = stage + 16384 + rb * 128;
    f16x8 b0 = *(const f16x8*)(bp + (qb0 ^ sw));
    f16x8 b1 = *(const f16x8*)(bp + (qb1 ^ sw));
    f32x4 acc0 = {0.f, 0.f, 0.f, 0.f}, acc1 = {0.f, 0.f, 0.f, 0.f};
    acc0 = __builtin_amdgcn_mfma_f32_16x16x32_f16(a00, b0, acc0, 0, 0, 0);
    acc0 = __builtin_amdgcn_mfma_f32_16x16x32_f16(a01, b1, acc0, 0, 0, 0);
    acc1 = __builtin_amdgcn_mfma_f32_16x16x32_f16(a10, b0, acc1, 0, 0, 0);
    acc1 = __builtin_amdgcn_mfma_f32_16x16x32_f16(a11, b1, acc1, 0, 0, 0);
    float csc = 0.f;
#pragma unroll
    for (int g = 0; g < 2; ++g) {
      f32x4 v = g ? acc1 : acc0;
#pragma unroll
      for (int r = 0; r < 4; ++r) {
        float bse = fminf(fmaf(v[r], keps, xnk[g][r]) + ynk[c], 0.f);
        rs[g][r] += __builtin_amdgcn_exp2f(bse + hr[c] - rmv[g][r]);
        csc += __builtin_amdgcn_exp2f(bse + hcv[g][r] - cmv[c]);
      }
    }
    cs8[c] = csc;
  }

  // row sums: butterfly over 16 lanes; lanes m==0 write the row partials
#pragma unroll
  for (int g = 0; g < 2; ++g)
#pragma unroll
    for (int r = 0; r < 4; ++r) {
      float v = rs[g][r];
      v += __shfl_xor(v, 1);
      v += __shfl_xor(v, 2);
      v += __shfl_xor(v, 4);
      v += __shfl_xor(v, 8);
      rs[g][r] = v;
    }
  if (m == 0) {
    float2* pr = A.prow + ((size_t)b * NCHK + J) * NN + i0;
#pragma unroll
    for (int g = 0; g < 2; ++g)
#pragma unroll
      for (int r = 0; r < 4; ++r) {
        int row = 32 * w + 16 * g + 4 * quad + r;
        pr[row] = make_float2(rmv[g][r], rs[g][r]);
      }
  }

  // col sums: quad-reduce in-wave, 4-wave merge, coalesced pcol write
#pragma unroll
  for (int c = 0; c < 8; ++c) {
    float v = cs8[c];
    v += __shfl_xor(v, 16);
    v += __shfl_xor(v, 32);
    cs8[c] = v;
  }
  if (quad == 0) {
#pragma unroll
    for (int c = 0; c < 8; ++c) csumw[16 * c + m][w] = cs8[c];
  }
  __syncthreads();
  if (t < TS && !(A.sym && I == J)) {   // diagonal col-dir duplicates row-dir
    float4 mq = *(const float4*)cmaxw[t];
    float4 sq = *(const float4*)csumw[t];
    float M = fmaxf(fmaxf(mq.x, mq.y), fmaxf(mq.z, mq.w));
    float S = sq.x + sq.y + sq.z + sq.w;
    A.pcol[((size_t)b * NCHK + I) * NN + j0 + t] = make_float2(M, S);
  }
}

// ---------------------------------------------------------------------------
// merge 16 chunk-partials per row -> softmin + Jacobi update + next-h write.
// Partials in log2 domain: ft = -eps*ln2*(M + log2(S)).
// ---------------------------------------------------------------------------
struct MergeArgs {
  const float2* part;
  const float* fold;
  float* fout;
  const float* hbase;   // alog or blog (log2 domain)
  float* hout;          // h vector consumed by the next tile_fused
};

__global__ __launch_bounds__(256) void merge4(
    MergeArgs M0, MergeArgs M1, MergeArgs M2, MergeArgs M3,
    float eps, float alpha, float beta, float nextgs)
{
  MergeArgs A = (blockIdx.z == 0) ? M0 : (blockIdx.z == 1) ? M1
              : (blockIdx.z == 2) ? M2 : M3;
  const int b = blockIdx.y;
  const int i = blockIdx.x * 256 + threadIdx.x;   // grid.x = NN/256
  float2 p[NCHK];
#pragma unroll
  for (int k = 0; k < NCHK; ++k)
    p[k] = A.part[((size_t)b * NCHK + k) * NN + i];
  float M = p[0].x;
#pragma unroll
  for (int k = 1; k < NCHK; ++k) M = fmaxf(M, p[k].x);
  float S = 0.f;
#pragma unroll
  for (int k = 0; k < NCHK; ++k) S += p[k].y * __builtin_amdgcn_exp2f(p[k].x - M);
  float ft = (-LN2 * eps) * (M + __log2f(S));
  int idx = b * NN + i;
  float fnew = alpha * A.fold[idx] + beta * ft;
  A.fout[idx] = fnew;
  A.hout[idx] = fmaf(nextgs * L2E, fnew, A.hbase[idx]);
}

// ---------------------------------------------------------------------------
__global__ __launch_bounds__(256) void loss_kernel(
    const float* __restrict__ w1, const float* __restrict__ w2,
    float* __restrict__ out)
{
  __shared__ float red[256];
  float acc = 0.f;
  for (int idx = threadIdx.x; idx < NB * NN; idx += 256) {
    acc += w1[idx] * (g_fab[2][idx] - g_faa[2][idx])
         + w2[idx] * (g_gba[2][idx] - g_gbb[2][idx]);
  }
  red[threadIdx.x] = acc;
  __syncthreads();
  for (int s = 128; s > 0; s >>= 1) {
    if (threadIdx.x < s) red[threadIdx.x] += red[threadIdx.x + s];
    __syncthreads();
  }
  if (threadIdx.x == 0) out[0] = red[0] * (1.0f / NB);
}

// ---------------------------------------------------------------------------
extern "C" void kernel_launch(void* const* d_in, const int* in_sizes, int n_in,
                              void* d_out, int out_size, void* d_ws, size_t ws_size,
                              hipStream_t stream)
{
  const float* x = (const float*)d_in[0];
  const float* y = (const float*)d_in[1];
  const float* w1 = (const float*)d_in[2];
  const float* w2 = (const float*)d_in[3];
  float* out = (float*)d_out;

  half_t *xh, *yh;
  float *xn, *yn;
  float *h0, *h1, *h2, *h3, *fabp, *gbap, *faap, *gbbp, *alog, *blog;
  float2 *pfab, *pgba, *pfaa, *pgbb;
  hipGetSymbolAddress((void**)&xh, HIP_SYMBOL(g_xh));
  hipGetSymbolAddress((void**)&yh, HIP_SYMBOL(g_yh));
  hipGetSymbolAddress((void**)&xn, HIP_SYMBOL(g_xn));
  hipGetSymbolAddress((void**)&yn, HIP_SYMBOL(g_yn));
  hipGetSymbolAddress((void**)&h0, HIP_SYMBOL(g_h0));
  hipGetSymbolAddress((void**)&h1, HIP_SYMBOL(g_h1));
  hipGetSymbolAddress((void**)&h2, HIP_SYMBOL(g_h2));
  hipGetSymbolAddress((void**)&h3, HIP_SYMBOL(g_h3));
  hipGetSymbolAddress((void**)&fabp, HIP_SYMBOL(g_fab));
  hipGetSymbolAddress((void**)&gbap, HIP_SYMBOL(g_gba));
  hipGetSymbolAddress((void**)&faap, HIP_SYMBOL(g_faa));
  hipGetSymbolAddress((void**)&gbbp, HIP_SYMBOL(g_gbb));
  hipGetSymbolAddress((void**)&alog, HIP_SYMBOL(g_alog));
  hipGetSymbolAddress((void**)&blog, HIP_SYMBOL(g_blog));
  hipGetSymbolAddress((void**)&pfab, HIP_SYMBOL(g_pfab));
  hipGetSymbolAddress((void**)&pgba, HIP_SYMBOL(g_pgba));
  hipGetSymbolAddress((void**)&pfaa, HIP_SYMBOL(g_pfaa));
  hipGetSymbolAddress((void**)&pgbb, HIP_SYMBOL(g_pgbb));

  auto fab = [&](int s) { return fabp + (size_t)s * NB * NN; };
  auto gba = [&](int s) { return gbap + (size_t)s * NB * NN; };
  auto faa = [&](int s) { return faap + (size_t)s * NB * NN; };
  auto gbb = [&](int s) { return gbbp + (size_t)s * NB * NN; };

  // eps schedule (matches the Python double loop, then cast to fp32)
  float eps_list[32];
  int ne = 0;
  {
    double v = 64.0 * 64.0;
    double tgt = 0.05 * 0.05;
    while (v > tgt) { eps_list[ne++] = (float)v; v *= 0.25; }
    eps_list[ne++] = (float)tgt;   // ne == 12
  }

  prep_kernel<<<4096, 256, 0, stream>>>(x, y, w1, w2);

  dim3 tg(4224);                // flattened: 2048 xy + 1088 xx + 1088 yy
  dim3 mg(NN / 256, NB, 4);     // z: potential

  auto launch_iter = [&](float eps, float alpha, float beta, float nextgs,
                         int in, int outsel) {
    float keps = L2E / eps;
    FusedArgs T0 = {xh, yh, xn, yn, h0, h1, pfab, pgba, 0};
    FusedArgs T1 = {xh, xh, xn, xn, h2, h2, pfaa, pfaa, 1};
    FusedArgs T2 = {yh, yh, yn, yn, h3, h3, pgbb, pgbb, 1};
    tile_fused<<<tg, 256, 0, stream>>>(T0, T1, T2, keps);
    MergeArgs M0 = {pfab, fab(in), fab(outsel), alog, h1};
    MergeArgs M1 = {pgba, gba(in), gba(outsel), blog, h0};
    MergeArgs M2 = {pfaa, faa(in), faa(outsel), alog, h2};
    MergeArgs M3 = {pgbb, gbb(in), gbb(outsel), blog, h3};
    merge4<<<mg, 256, 0, stream>>>(M0, M1, M2, M3, eps, alpha, beta, nextgs);
  };

  // init at eps0: h = base log2-weights (gs=0), alpha=0 -> no carry read;
  // its merge writes h for scan step k=0.
  hprep_kernel<<<64, 256, 0, stream>>>(fab(0), gba(0), faa(0), gbb(0), 0.f);
  launch_iter(eps_list[0], 0.f, 1.f, 1.0f / eps_list[0], 0, 0);

  // scan over the full eps list with 0.5-averaging (Jacobi, banks 0/1);
  // each merge writes h for the NEXT step (k+1, or the final extrapolation).
  int cur = 0;
  for (int k = 0; k < ne; ++k) {
    int nxt = 1 - cur;
    float nextgs = 1.0f / ((k < ne - 1) ? eps_list[k + 1] : eps_list[ne - 1]);
    launch_iter(eps_list[k], 0.5f, 0.5f, nextgs, cur, nxt);
    cur = nxt;
  }

  // final extrapolation at eps = blur^p (no averaging) -> bank 2
  launch_iter(eps_list[ne - 1], 0.f, 1.f, 0.f, cur, 2);

  loss_kernel<<<1, 256, 0, stream>>>(w1, w2, out);
}

// Round 5
// 712.926 us; speedup vs baseline: 1.5355x; 1.2079x over previous
//
#include <hip/hip_runtime.h>

#define NB 8
#define NN 2048
#define MM 2048
#define DD 64
#define NCHK 16
#define TS 128
#define L2E 1.4426950408889634f
#define LN2 0.6931471805599453f

typedef _Float16 half_t;
typedef __attribute__((ext_vector_type(8))) _Float16 f16x8;
typedef __attribute__((ext_vector_type(4))) float f32x4;
typedef __attribute__((ext_vector_type(2))) float f32x2;

__device__ inline f32x2 lo2(f32x4 v) { return __builtin_shufflevector(v, v, 0, 1); }
__device__ inline f32x2 hi2(f32x4 v) { return __builtin_shufflevector(v, v, 2, 3); }

// ---------------------------------------------------------------------------
// Static device scratch. C never materialized. Single MFMA pass per tile;
// acc kept in regs (32/thread at 512-thread blocks). Reductions via LDS
// transpose arrays aliased into the dead stage buffer (shfl chains proved
// VALU-expensive in round 4: ds_bpermute + moves). Phase A/B math on f32x2
// pairs to exploit v_pk_fma_f32 / v_pk_add_f32.
// ---------------------------------------------------------------------------
__device__ half_t g_xh[NB * NN * DD];           // fp16 copies for MFMA
__device__ half_t g_yh[NB * MM * DD];
__device__ float g_fab[3][NB * NN], g_gba[3][NB * NN];
__device__ float g_faa[3][NB * NN], g_gbb[3][NB * NN];
__device__ float g_alog[NB * NN], g_blog[NB * NN];   // log2(w)
__device__ float g_xn[NB * NN], g_yn[NB * NN];       // 0.5*||row||^2 (natural)
__device__ float g_h0[NB * MM], g_h1[NB * NN], g_h2[NB * NN], g_h3[NB * MM];
// chunked softmin partials (m,s) in log2 domain: [b][chunk][row]
__device__ float2 g_pfab[NB * NCHK * NN];
__device__ float2 g_pgba[NB * NCHK * NN];
__device__ float2 g_pfaa[NB * NCHK * NN];
__device__ float2 g_pgbb[NB * NCHK * NN];

// ---------------------------------------------------------------------------
__global__ __launch_bounds__(256) void prep_kernel(
    const float* __restrict__ x, const float* __restrict__ y,
    const float* __restrict__ w1, const float* __restrict__ w2)
{
  int gid = blockIdx.x * 256 + threadIdx.x;
  if (gid < NB * NN) {
    g_alog[gid] = log2f(w1[gid]);
    g_blog[gid] = log2f(w2[gid]);
  }
  int lane = threadIdx.x & 63;
  int row = blockIdx.x * 4 + (threadIdx.x >> 6);   // grid 4096 -> rows 0..16383
  float xv = x[(size_t)row * DD + lane];
  float yv = y[(size_t)row * DD + lane];
  g_xh[(size_t)row * DD + lane] = (half_t)xv;
  g_yh[(size_t)row * DD + lane] = (half_t)yv;
  float sx = xv * xv;
  float sy = yv * yv;
#pragma unroll
  for (int off = 32; off > 0; off >>= 1) {
    sx += __shfl_down(sx, off);
    sy += __shfl_down(sy, off);
  }
  if (lane == 0) {
    g_xn[row] = 0.5f * sx;
    g_yn[row] = 0.5f * sy;
  }
}

// ---------------------------------------------------------------------------
__global__ __launch_bounds__(256) void hprep_kernel(
    const float* __restrict__ fab_in, const float* __restrict__ gba_in,
    const float* __restrict__ faa_in, const float* __restrict__ gbb_in,
    float gs2)
{
  int i = blockIdx.x * 256 + threadIdx.x;   // grid 64 -> 16384
  g_h0[i] = fmaf(gs2, gba_in[i], g_blog[i]);
  g_h1[i] = fmaf(gs2, fab_in[i], g_alog[i]);
  g_h2[i] = fmaf(gs2, faa_in[i], g_alog[i]);
  g_h3[i] = fmaf(gs2, gbb_in[i], g_blog[i]);
}

// ---------------------------------------------------------------------------
// Fused cost-recompute + tile-partial softmin. 512 threads (8 waves), one
// 128x128 tile per block; wave w owns rows 16w..16w+15 (acc[8] f32x4 = 32
// VGPR). Single MFMA pass; bse stored in-place in acc for phase B.
// ---------------------------------------------------------------------------
struct FusedArgs {
  const half_t* Af;     // fragment rows (x or y)
  const half_t* Bf;     // fragment cols
  const float* nrow;    // xn or yn for rows
  const float* ncol;    // for cols
  const float* hrow;    // h over cols (row direction softmin), log2 dom.
  const float* hcol;    // h over rows
  float2* prow;         // [b][chunk][row]
  float2* pcol;
  int sym;              // 1 => diagonal col-dir partial is skipped
};

__global__ __launch_bounds__(512) void tile_fused(
    FusedArgs T0, FusedArgs T1, FusedArgs T2, float keps)   // keps = log2e/eps
{
  // flattened grid: 2048 xy tiles + 2*1088 triangular tiles = 4224 blocks
  int u = blockIdx.x;
  int slab, b, I, J;
  if (u < 2048) {
    slab = 0; b = u >> 8;
    int tt = u & 255; I = tt >> 4; J = tt & 15;
  } else {
    int v = u - 2048;
    slab = 1 + v / 1088;
    int w2 = v % 1088;
    b = w2 / 136;
    int rem = w2 % 136, ii = 0;
    while (rem >= NCHK - ii) { rem -= NCHK - ii; ++ii; }   // uniform, <=16 iters
    I = ii; J = ii + rem;                                  // I <= J
  }
  FusedArgs A = (slab == 0) ? T0 : (slab == 1) ? T1 : T2;

  const int t = threadIdx.x;
  const int w = t >> 6, lane = t & 63;
  const int m = lane & 15, quad = lane >> 4;
  const int i0 = I * TS, j0 = J * TS;

  // 32 KB: stage(A|B) while MFMA runs, then aliased reduction arrays.
  __shared__ __align__(16) char sh[32768];
  float* redR = (float*)sh;                  // [128][17]  (8704 B)
  float* redC = (float*)(sh + 8704);         // [128][33]  (16896 B)
  float* rowM = (float*)(sh + 25600);        // [128]
  float* colM = (float*)(sh + 26112);        // [128]

  // ---- stage A (16 KB) + B (16 KB) via global_load_lds, swizzled source ----
  {
    const char* gA = (const char*)(A.Af + ((size_t)b * NN + i0) * DD);
    const char* gB = (const char*)(A.Bf + ((size_t)b * MM + j0) * DD);
#pragma unroll
    for (int k = 0; k < 4; ++k) {
      int seg = w * 4 + k;                       // wave-uniform, 0..31
      int p = (seg * 1024 + lane * 16) & 16383;  // byte pos within buffer
      int row = p >> 7, colb = p & 127;
      int colx = colb ^ ((row & 7) << 4);
      const char* src = (seg < 16 ? gA : gB) + (size_t)row * 128 + colx;
      __builtin_amdgcn_global_load_lds(
          (const __attribute__((address_space(1))) unsigned int*)src,
          (__attribute__((address_space(3))) unsigned int*)(sh + seg * 1024),
          16, 0, 0);
    }
  }

  // ---- per-thread row/col scalars (overlap with staging DMA) ----
  size_t ro = (size_t)b * NN + i0 + 16 * w + 4 * quad;
  float4 xr = *(const float4*)(A.nrow + ro);
  float4 hq = *(const float4*)(A.hcol + ro);
  float ynk[8], hr[8];
#pragma unroll
  for (int c = 0; c < 8; ++c) {
    size_t co = (size_t)b * MM + j0 + 16 * c + m;
    ynk[c] = -A.ncol[co] * keps;
    hr[c] = A.hrow[co];
  }
  f32x2 xnkp0 = {-xr.x * keps, -xr.y * keps};
  f32x2 xnkp1 = {-xr.z * keps, -xr.w * keps};
  f32x2 hcp0 = {hq.x, hq.y}, hcp1 = {hq.z, hq.w};

  __syncthreads();   // #1: staging complete

  // ---- A fragments (rows 16w+m), both k-halves ----
  const int qb0 = quad * 16, qb1 = qb0 + 64;
  const int ra = 16 * w + m, sa = (ra & 7) << 4;
  f16x8 a0 = *(const f16x8*)(sh + ra * 128 + (qb0 ^ sa));
  f16x8 a1 = *(const f16x8*)(sh + ra * 128 + (qb1 ^ sa));

  // ---- MFMA: one pass, acc[8] (B rows 16c+m; 16c%8==0 so swz = m&7) ----
  const int sb = (m & 7) << 4;
  const char* bb = sh + 16384 + m * 128;
  f32x4 acc[8];
#pragma unroll
  for (int c = 0; c < 8; ++c) {
    f16x8 b0 = *(const f16x8*)(bb + c * 2048 + (qb0 ^ sb));
    f16x8 b1 = *(const f16x8*)(bb + c * 2048 + (qb1 ^ sb));
    f32x4 a = {0.f, 0.f, 0.f, 0.f};
    a = __builtin_amdgcn_mfma_f32_16x16x32_f16(a0, b0, a, 0, 0, 0);
    a = __builtin_amdgcn_mfma_f32_16x16x32_f16(a1, b1, a, 0, 0, 0);
    acc[c] = a;
  }

  // ---- phase A: base (kept in acc) + row/col maxes, packed-f32 pairs ----
  const f32x2 kv = {keps, keps};
  const f32x2 zz = {0.f, 0.f};
  f32x2 rmp0 = {-3.0e38f, -3.0e38f}, rmp1 = {-3.0e38f, -3.0e38f};
  float cm[8];
#pragma unroll
  for (int c = 0; c < 8; ++c) {
    f32x2 ay0 = xnkp0 + ynk[c];
    f32x2 ay1 = xnkp1 + ynk[c];
    f32x2 q0 = __builtin_elementwise_fma(lo2(acc[c]), kv, ay0);
    f32x2 q1 = __builtin_elementwise_fma(hi2(acc[c]), kv, ay1);
    f32x2 b0 = __builtin_elementwise_min(q0, zz);
    f32x2 b1 = __builtin_elementwise_min(q1, zz);
    acc[c] = __builtin_shufflevector(b0, b1, 0, 1, 2, 3);   // bse kept
    f32x2 rv0 = b0 + hr[c];
    f32x2 rv1 = b1 + hr[c];
    rmp0 = __builtin_elementwise_max(rmp0, rv0);
    rmp1 = __builtin_elementwise_max(rmp1, rv1);
    f32x2 cv0 = b0 + hcp0;
    f32x2 cv1 = b1 + hcp1;
    cm[c] = fmaxf(fmaxf(cv0.x, cv0.y), fmaxf(cv1.x, cv1.y));
  }

  __syncthreads();   // #2: all stage reads done -> safe to alias

  // phase A partials
  {
    int rbase = (16 * w + 4 * quad) * 17 + m;
    redR[rbase] = rmp0.x; redR[rbase + 17] = rmp0.y;
    redR[rbase + 34] = rmp1.x; redR[rbase + 51] = rmp1.y;
    int cidx = m * 33 + 4 * w + quad;
#pragma unroll
    for (int c = 0; c < 8; ++c) redC[cidx + c * 528] = cm[c];
  }
  __syncthreads();   // #3

  if (t < 128) {
    float mx = redR[t * 17];
#pragma unroll
    for (int k = 1; k < 16; ++k) mx = fmaxf(mx, redR[t * 17 + k]);
    rowM[t] = mx;
  } else if (t < 256) {
    int cc = t - 128;
    float mx = redC[cc * 33];
#pragma unroll
    for (int k = 1; k < 32; ++k) mx = fmaxf(mx, redC[cc * 33 + k]);
    colM[cc] = mx;
  }
  __syncthreads();   // #4

  // ---- phase B: exp2 sums from bse still in acc ----
  float4 rq = *(const float4*)(rowM + 16 * w + 4 * quad);
  f32x2 rmv0 = {rq.x, rq.y}, rmv1 = {rq.z, rq.w};
  float cmv[8];
#pragma unroll
  for (int c = 0; c < 8; ++c) cmv[c] = colM[16 * c + m];

  f32x2 rsp0 = {0.f, 0.f}, rsp1 = {0.f, 0.f};
  float cs[8];
#pragma unroll
  for (int c = 0; c < 8; ++c) {
    f32x2 hrm0 = hr[c] - rmv0;          // hoisted per c (pk_sub)
    f32x2 hrm1 = hr[c] - rmv1;
    f32x2 chm0 = hcp0 - cmv[c];
    f32x2 chm1 = hcp1 - cmv[c];
    f32x2 b0 = lo2(acc[c]), b1 = hi2(acc[c]);
    f32x2 t0 = b0 + hrm0, t1 = b1 + hrm1;
    float e0 = __builtin_amdgcn_exp2f(t0.x), e1 = __builtin_amdgcn_exp2f(t0.y);
    float e2 = __builtin_amdgcn_exp2f(t1.x), e3 = __builtin_amdgcn_exp2f(t1.y);
    f32x2 ep0 = {e0, e1}, ep1 = {e2, e3};
    rsp0 += ep0; rsp1 += ep1;
    f32x2 u0 = b0 + chm0, u1 = b1 + chm1;
    float f0 = __builtin_amdgcn_exp2f(u0.x), f1 = __builtin_amdgcn_exp2f(u0.y);
    float f2 = __builtin_amdgcn_exp2f(u1.x), f3 = __builtin_amdgcn_exp2f(u1.y);
    cs[c] = (f0 + f1) + (f2 + f3);
  }

  // phase B partials (redR/redC reuse: last read was before barrier #4)
  {
    int rbase = (16 * w + 4 * quad) * 17 + m;
    redR[rbase] = rsp0.x; redR[rbase + 17] = rsp0.y;
    redR[rbase + 34] = rsp1.x; redR[rbase + 51] = rsp1.y;
    int cidx = m * 33 + 4 * w + quad;
#pragma unroll
    for (int c = 0; c < 8; ++c) redC[cidx + c * 528] = cs[c];
  }
  __syncthreads();   // #5

  if (t < 128) {
    float s = 0.f;
#pragma unroll
    for (int k = 0; k < 16; ++k) s += redR[t * 17 + k];
    A.prow[((size_t)b * NCHK + J) * NN + i0 + t] = make_float2(rowM[t], s);
  } else if (t < 256) {
    if (!(A.sym && I == J)) {   // diagonal col-dir duplicates row-dir: skip
      int cc = t - 128;
      float s = 0.f;
#pragma unroll
      for (int k = 0; k < 32; ++k) s += redC[cc * 33 + k];
      A.pcol[((size_t)b * NCHK + I) * NN + j0 + cc] = make_float2(colM[cc], s);
    }
  }
}

// ---------------------------------------------------------------------------
// merge 16 chunk-partials per row -> softmin + Jacobi update + next-h write.
// Partials in log2 domain: ft = -eps*ln2*(M + log2(S)).
// ---------------------------------------------------------------------------
struct MergeArgs {
  const float2* part;
  const float* fold;
  float* fout;
  const float* hbase;   // alog or blog (log2 domain)
  float* hout;          // h vector consumed by the next tile_fused
};

__global__ __launch_bounds__(256) void merge4(
    MergeArgs M0, MergeArgs M1, MergeArgs M2, MergeArgs M3,
    float eps, float alpha, float beta, float nextgs)
{
  MergeArgs A = (blockIdx.z == 0) ? M0 : (blockIdx.z == 1) ? M1
              : (blockIdx.z == 2) ? M2 : M3;
  const int b = blockIdx.y;
  const int i = blockIdx.x * 256 + threadIdx.x;   // grid.x = NN/256
  float2 p[NCHK];
#pragma unroll
  for (int k = 0; k < NCHK; ++k)
    p[k] = A.part[((size_t)b * NCHK + k) * NN + i];
  float M = p[0].x;
#pragma unroll
  for (int k = 1; k < NCHK; ++k) M = fmaxf(M, p[k].x);
  float S = 0.f;
#pragma unroll
  for (int k = 0; k < NCHK; ++k) S += p[k].y * __builtin_amdgcn_exp2f(p[k].x - M);
  float ft = (-LN2 * eps) * (M + __log2f(S));
  int idx = b * NN + i;
  float fnew = alpha * A.fold[idx] + beta * ft;
  A.fout[idx] = fnew;
  A.hout[idx] = fmaf(nextgs * L2E, fnew, A.hbase[idx]);
}

// ---------------------------------------------------------------------------
__global__ __launch_bounds__(256) void loss_kernel(
    const float* __restrict__ w1, const float* __restrict__ w2,
    float* __restrict__ out)
{
  __shared__ float red[256];
  float acc = 0.f;
  for (int idx = threadIdx.x; idx < NB * NN; idx += 256) {
    acc += w1[idx] * (g_fab[2][idx] - g_faa[2][idx])
         + w2[idx] * (g_gba[2][idx] - g_gbb[2][idx]);
  }
  red[threadIdx.x] = acc;
  __syncthreads();
  for (int s = 128; s > 0; s >>= 1) {
    if (threadIdx.x < s) red[threadIdx.x] += red[threadIdx.x + s];
    __syncthreads();
  }
  if (threadIdx.x == 0) out[0] = red[0] * (1.0f / NB);
}

// ---------------------------------------------------------------------------
extern "C" void kernel_launch(void* const* d_in, const int* in_sizes, int n_in,
                              void* d_out, int out_size, void* d_ws, size_t ws_size,
                              hipStream_t stream)
{
  const float* x = (const float*)d_in[0];
  const float* y = (const float*)d_in[1];
  const float* w1 = (const float*)d_in[2];
  const float* w2 = (const float*)d_in[3];
  float* out = (float*)d_out;

  half_t *xh, *yh;
  float *xn, *yn;
  float *h0, *h1, *h2, *h3, *fabp, *gbap, *faap, *gbbp, *alog, *blog;
  float2 *pfab, *pgba, *pfaa, *pgbb;
  hipGetSymbolAddress((void**)&xh, HIP_SYMBOL(g_xh));
  hipGetSymbolAddress((void**)&yh, HIP_SYMBOL(g_yh));
  hipGetSymbolAddress((void**)&xn, HIP_SYMBOL(g_xn));
  hipGetSymbolAddress((void**)&yn, HIP_SYMBOL(g_yn));
  hipGetSymbolAddress((void**)&h0, HIP_SYMBOL(g_h0));
  hipGetSymbolAddress((void**)&h1, HIP_SYMBOL(g_h1));
  hipGetSymbolAddress((void**)&h2, HIP_SYMBOL(g_h2));
  hipGetSymbolAddress((void**)&h3, HIP_SYMBOL(g_h3));
  hipGetSymbolAddress((void**)&fabp, HIP_SYMBOL(g_fab));
  hipGetSymbolAddress((void**)&gbap, HIP_SYMBOL(g_gba));
  hipGetSymbolAddress((void**)&faap, HIP_SYMBOL(g_faa));
  hipGetSymbolAddress((void**)&gbbp, HIP_SYMBOL(g_gbb));
  hipGetSymbolAddress((void**)&alog, HIP_SYMBOL(g_alog));
  hipGetSymbolAddress((void**)&blog, HIP_SYMBOL(g_blog));
  hipGetSymbolAddress((void**)&pfab, HIP_SYMBOL(g_pfab));
  hipGetSymbolAddress((void**)&pgba, HIP_SYMBOL(g_pgba));
  hipGetSymbolAddress((void**)&pfaa, HIP_SYMBOL(g_pfaa));
  hipGetSymbolAddress((void**)&pgbb, HIP_SYMBOL(g_pgbb));

  auto fab = [&](int s) { return fabp + (size_t)s * NB * NN; };
  auto gba = [&](int s) { return gbap + (size_t)s * NB * NN; };
  auto faa = [&](int s) { return faap + (size_t)s * NB * NN; };
  auto gbb = [&](int s) { return gbbp + (size_t)s * NB * NN; };

  // eps schedule (matches the Python double loop, then cast to fp32)
  float eps_list[32];
  int ne = 0;
  {
    double v = 64.0 * 64.0;
    double tgt = 0.05 * 0.05;
    while (v > tgt) { eps_list[ne++] = (float)v; v *= 0.25; }
    eps_list[ne++] = (float)tgt;   // ne == 12
  }

  prep_kernel<<<4096, 256, 0, stream>>>(x, y, w1, w2);

  dim3 tg(4224);                // flattened: 2048 xy + 1088 xx + 1088 yy
  dim3 mg(NN / 256, NB, 4);     // z: potential

  auto launch_iter = [&](float eps, float alpha, float beta, float nextgs,
                         int in, int outsel) {
    float keps = L2E / eps;
    FusedArgs T0 = {xh, yh, xn, yn, h0, h1, pfab, pgba, 0};
    FusedArgs T1 = {xh, xh, xn, xn, h2, h2, pfaa, pfaa, 1};
    FusedArgs T2 = {yh, yh, yn, yn, h3, h3, pgbb, pgbb, 1};
    tile_fused<<<tg, 512, 0, stream>>>(T0, T1, T2, keps);
    MergeArgs M0 = {pfab, fab(in), fab(outsel), alog, h1};
    MergeArgs M1 = {pgba, gba(in), gba(outsel), blog, h0};
    MergeArgs M2 = {pfaa, faa(in), faa(outsel), alog, h2};
    MergeArgs M3 = {pgbb, gbb(in), gbb(outsel), blog, h3};
    merge4<<<mg, 256, 0, stream>>>(M0, M1, M2, M3, eps, alpha, beta, nextgs);
  };

  // init at eps0: h = base log2-weights (gs=0), alpha=0 -> no carry read;
  // its merge writes h for scan step k=0.
  hprep_kernel<<<64, 256, 0, stream>>>(fab(0), gba(0), faa(0), gbb(0), 0.f);
  launch_iter(eps_list[0], 0.f, 1.f, 1.0f / eps_list[0], 0, 0);

  // scan over the full eps list with 0.5-averaging (Jacobi, banks 0/1);
  // each merge writes h for the NEXT step (k+1, or the final extrapolation).
  int cur = 0;
  for (int k = 0; k < ne; ++k) {
    int nxt = 1 - cur;
    float nextgs = 1.0f / ((k < ne - 1) ? eps_list[k + 1] : eps_list[ne - 1]);
    launch_iter(eps_list[k], 0.5f, 0.5f, nextgs, cur, nxt);
    cur = nxt;
  }

  // final extrapolation at eps = blur^p (no averaging) -> bank 2
  launch_iter(eps_list[ne - 1], 0.f, 1.f, 0.f, cur, 2);

  loss_kernel<<<1, 256, 0, stream>>>(w1, w2, out);
}

// Round 6
// 661.730 us; speedup vs baseline: 1.6543x; 1.0774x over previous
//
#include <hip/hip_runtime.h>

#define NB 8
#define NN 2048
#define MM 2048
#define DD 64
#define NCHK 16
#define TS 128
#define L2E 1.4426950408889634f
#define LN2 0.6931471805599453f

typedef _Float16 half_t;
typedef __attribute__((ext_vector_type(8))) _Float16 f16x8;
typedef __attribute__((ext_vector_type(4))) float f32x4;
typedef __attribute__((ext_vector_type(2))) float f32x2;

__device__ inline f32x2 lo2(f32x4 v) { return __builtin_shufflevector(v, v, 0, 1); }
__device__ inline f32x2 hi2(f32x4 v) { return __builtin_shufflevector(v, v, 2, 3); }

// ---------------------------------------------------------------------------
// Static device scratch. C never materialized. Register budget engineered to
// total <= 64 (VGPR + acc-AGPR) so each SIMD fits 8 waves (occupancy granule
// steps at 64/128/256 — round 5 measured 72 regs -> 16 waves/CU -> 49%).
// Held scalar arrays (ynk[8], hr[8]) moved to small LDS tables; per-column
// partials (cm/cs) written to LDS immediately instead of being held.
// ---------------------------------------------------------------------------
__device__ half_t g_xh[NB * NN * DD];           // fp16 copies for MFMA
__device__ half_t g_yh[NB * MM * DD];
__device__ float g_fab[3][NB * NN], g_gba[3][NB * NN];
__device__ float g_faa[3][NB * NN], g_gbb[3][NB * NN];
__device__ float g_alog[NB * NN], g_blog[NB * NN];   // log2(w)
__device__ float g_xn[NB * NN], g_yn[NB * NN];       // 0.5*||row||^2 (natural)
__device__ float g_h0[NB * MM], g_h1[NB * NN], g_h2[NB * NN], g_h3[NB * MM];
// chunked softmin partials (m,s) in log2 domain: [b][chunk][row]
__device__ float2 g_pfab[NB * NCHK * NN];
__device__ float2 g_pgba[NB * NCHK * NN];
__device__ float2 g_pfaa[NB * NCHK * NN];
__device__ float2 g_pgbb[NB * NCHK * NN];

// ---------------------------------------------------------------------------
__global__ __launch_bounds__(256) void prep_kernel(
    const float* __restrict__ x, const float* __restrict__ y,
    const float* __restrict__ w1, const float* __restrict__ w2)
{
  int gid = blockIdx.x * 256 + threadIdx.x;
  if (gid < NB * NN) {
    g_alog[gid] = log2f(w1[gid]);
    g_blog[gid] = log2f(w2[gid]);
  }
  int lane = threadIdx.x & 63;
  int row = blockIdx.x * 4 + (threadIdx.x >> 6);   // grid 4096 -> rows 0..16383
  float xv = x[(size_t)row * DD + lane];
  float yv = y[(size_t)row * DD + lane];
  g_xh[(size_t)row * DD + lane] = (half_t)xv;
  g_yh[(size_t)row * DD + lane] = (half_t)yv;
  float sx = xv * xv;
  float sy = yv * yv;
#pragma unroll
  for (int off = 32; off > 0; off >>= 1) {
    sx += __shfl_down(sx, off);
    sy += __shfl_down(sy, off);
  }
  if (lane == 0) {
    g_xn[row] = 0.5f * sx;
    g_yn[row] = 0.5f * sy;
  }
}

// ---------------------------------------------------------------------------
__global__ __launch_bounds__(256) void hprep_kernel(
    const float* __restrict__ fab_in, const float* __restrict__ gba_in,
    const float* __restrict__ faa_in, const float* __restrict__ gbb_in,
    float gs2)
{
  int i = blockIdx.x * 256 + threadIdx.x;   // grid 64 -> 16384
  g_h0[i] = fmaf(gs2, gba_in[i], g_blog[i]);
  g_h1[i] = fmaf(gs2, fab_in[i], g_alog[i]);
  g_h2[i] = fmaf(gs2, faa_in[i], g_alog[i]);
  g_h3[i] = fmaf(gs2, gbb_in[i], g_blog[i]);
}

// ---------------------------------------------------------------------------
// Fused cost-recompute + tile-partial softmin. 512 threads (8 waves), one
// 128x128 tile; wave w rows 16w..16w+15. acc[8] f32x4 = 32 AGPR holds
// dot->bse across phases; all other per-c scalars come from LDS tables.
// ---------------------------------------------------------------------------
struct FusedArgs {
  const half_t* Af;     // fragment rows (x or y)
  const half_t* Bf;     // fragment cols
  const float* nrow;    // xn or yn for rows
  const float* ncol;    // for cols
  const float* hrow;    // h over cols (row direction softmin), log2 dom.
  const float* hcol;    // h over rows
  float2* prow;         // [b][chunk][row]
  float2* pcol;
  int sym;              // 1 => diagonal col-dir partial is skipped
};

__global__ __launch_bounds__(512) void tile_fused(
    FusedArgs T0, FusedArgs T1, FusedArgs T2, float keps)   // keps = log2e/eps
{
  // flattened grid: 2048 xy tiles + 2*1088 triangular tiles = 4224 blocks
  int u = blockIdx.x;
  int slab, b, I, J;
  if (u < 2048) {
    slab = 0; b = u >> 8;
    int tt = u & 255; I = tt >> 4; J = tt & 15;
  } else {
    int v = u - 2048;
    slab = 1 + v / 1088;
    int w2 = v % 1088;
    b = w2 / 136;
    int rem = w2 % 136, ii = 0;
    while (rem >= NCHK - ii) { rem -= NCHK - ii; ++ii; }   // uniform, <=16 iters
    I = ii; J = ii + rem;                                  // I <= J
  }
  FusedArgs A = (slab == 0) ? T0 : (slab == 1) ? T1 : T2;

  const int t = threadIdx.x;
  const int w = t >> 6, lane = t & 63;
  const int m = lane & 15, quad = lane >> 4;
  const int i0 = I * TS, j0 = J * TS;

  // 33.75 KB LDS: 32 KB stage (A|B), aliased by reduction arrays after the
  // MFMA loop, plus persistent ynkL/hrL scalar tables at the tail.
  __shared__ __align__(16) char sh[33792];
  float* redR = (float*)sh;                  // [128][17]  (8704 B)
  float* redC = (float*)(sh + 8704);         // [128][33]  (16896 B)
  float* rowM = (float*)(sh + 25600);        // [128]
  float* colM = (float*)(sh + 26112);        // [128]
  float* ynkL = (float*)(sh + 32768);        // [128]  -ncol*keps
  float* hrL  = (float*)(sh + 33280);        // [128]  hrow slice

  // ---- stage A (16 KB) + B (16 KB) via global_load_lds, swizzled source ----
  {
    const char* gA = (const char*)(A.Af + ((size_t)b * NN + i0) * DD);
    const char* gB = (const char*)(A.Bf + ((size_t)b * MM + j0) * DD);
#pragma unroll
    for (int k = 0; k < 4; ++k) {
      int seg = w * 4 + k;                       // wave-uniform, 0..31
      int p = (seg * 1024 + lane * 16) & 16383;  // byte pos within buffer
      int row = p >> 7, colb = p & 127;
      int colx = colb ^ ((row & 7) << 4);
      const char* src = (seg < 16 ? gA : gB) + (size_t)row * 128 + colx;
      __builtin_amdgcn_global_load_lds(
          (const __attribute__((address_space(1))) unsigned int*)src,
          (__attribute__((address_space(3))) unsigned int*)(sh + seg * 1024),
          16, 0, 0);
    }
  }

  // ---- scalar tables + per-thread row scalars (overlap with DMA) ----
  if (t < 128) {
    ynkL[t] = -A.ncol[(size_t)b * MM + j0 + t] * keps;
  } else if (t < 256) {
    hrL[t - 128] = A.hrow[(size_t)b * MM + j0 + (t - 128)];
  }
  size_t ro = (size_t)b * NN + i0 + 16 * w + 4 * quad;
  float4 xr = *(const float4*)(A.nrow + ro);
  float4 hq = *(const float4*)(A.hcol + ro);
  f32x2 xnkp0 = {-xr.x * keps, -xr.y * keps};
  f32x2 xnkp1 = {-xr.z * keps, -xr.w * keps};
  f32x2 hcp0 = {hq.x, hq.y}, hcp1 = {hq.z, hq.w};

  __syncthreads();   // #1: staging + tables complete

  // ---- A fragments (rows 16w+m), both k-halves ----
  const int qb0 = quad * 16, qb1 = qb0 + 64;
  const int ra = 16 * w + m, sa = (ra & 7) << 4;
  f16x8 a0 = *(const f16x8*)(sh + ra * 128 + (qb0 ^ sa));
  f16x8 a1 = *(const f16x8*)(sh + ra * 128 + (qb1 ^ sa));

  // ---- MFMA: one pass, acc[8] (B rows 16c+m; 16c%8==0 so swz = m&7) ----
  const int sb = (m & 7) << 4;
  const char* bb = sh + 16384 + m * 128;
  f32x4 acc[8];
#pragma unroll
  for (int c = 0; c < 8; ++c) {
    f16x8 b0 = *(const f16x8*)(bb + c * 2048 + (qb0 ^ sb));
    f16x8 b1 = *(const f16x8*)(bb + c * 2048 + (qb1 ^ sb));
    f32x4 a = {0.f, 0.f, 0.f, 0.f};
    a = __builtin_amdgcn_mfma_f32_16x16x32_f16(a0, b0, a, 0, 0, 0);
    a = __builtin_amdgcn_mfma_f32_16x16x32_f16(a1, b1, a, 0, 0, 0);
    acc[c] = a;
  }

  __syncthreads();   // #2: all stage reads done -> redR/redC alias is safe

  // ---- phase A: base (kept in acc) + row maxes; col maxes -> LDS per c ----
  const f32x2 kv = {keps, keps};
  const f32x2 zz = {0.f, 0.f};
  f32x2 rmp0 = {-3.0e38f, -3.0e38f}, rmp1 = {-3.0e38f, -3.0e38f};
#pragma unroll
  for (int c = 0; c < 8; ++c) {
    float ynk_c = ynkL[16 * c + m];
    float hr_c = hrL[16 * c + m];
    f32x2 ay0 = xnkp0 + ynk_c;
    f32x2 ay1 = xnkp1 + ynk_c;
    f32x2 q0 = __builtin_elementwise_fma(lo2(acc[c]), kv, ay0);
    f32x2 q1 = __builtin_elementwise_fma(hi2(acc[c]), kv, ay1);
    f32x2 b0 = __builtin_elementwise_min(q0, zz);
    f32x2 b1 = __builtin_elementwise_min(q1, zz);
    acc[c] = __builtin_shufflevector(b0, b1, 0, 1, 2, 3);   // bse kept
    f32x2 rv0 = b0 + hr_c;
    f32x2 rv1 = b1 + hr_c;
    rmp0 = __builtin_elementwise_max(rmp0, rv0);
    rmp1 = __builtin_elementwise_max(rmp1, rv1);
    f32x2 cv0 = b0 + hcp0;
    f32x2 cv1 = b1 + hcp1;
    float cm_c = fmaxf(fmaxf(cv0.x, cv0.y), fmaxf(cv1.x, cv1.y));
    redC[(16 * c + m) * 33 + 4 * w + quad] = cm_c;   // write now, hold nothing
  }
  {
    int rbase = (16 * w + 4 * quad) * 17 + m;
    redR[rbase] = rmp0.x; redR[rbase + 17] = rmp0.y;
    redR[rbase + 34] = rmp1.x; redR[rbase + 51] = rmp1.y;
  }
  __syncthreads();   // #3

  if (t < 128) {
    float mx = redR[t * 17];
#pragma unroll
    for (int k = 1; k < 16; ++k) mx = fmaxf(mx, redR[t * 17 + k]);
    rowM[t] = mx;
  } else if (t < 256) {
    int cc = t - 128;
    float mx = redC[cc * 33];
#pragma unroll
    for (int k = 1; k < 32; ++k) mx = fmaxf(mx, redC[cc * 33 + k]);
    colM[cc] = mx;
  }
  __syncthreads();   // #4

  // ---- phase B: exp2 sums from bse still in acc; col sums -> LDS per c ----
  float4 rq = *(const float4*)(rowM + 16 * w + 4 * quad);
  f32x2 rmv0 = {rq.x, rq.y}, rmv1 = {rq.z, rq.w};
  f32x2 rsp0 = {0.f, 0.f}, rsp1 = {0.f, 0.f};
#pragma unroll
  for (int c = 0; c < 8; ++c) {
    float hr_c = hrL[16 * c + m];
    float cmv_c = colM[16 * c + m];
    f32x2 hrm0 = hr_c - rmv0;
    f32x2 hrm1 = hr_c - rmv1;
    f32x2 chm0 = hcp0 - cmv_c;
    f32x2 chm1 = hcp1 - cmv_c;
    f32x2 b0 = lo2(acc[c]), b1 = hi2(acc[c]);
    f32x2 t0 = b0 + hrm0, t1 = b1 + hrm1;
    float e0 = __builtin_amdgcn_exp2f(t0.x), e1 = __builtin_amdgcn_exp2f(t0.y);
    float e2 = __builtin_amdgcn_exp2f(t1.x), e3 = __builtin_amdgcn_exp2f(t1.y);
    f32x2 ep0 = {e0, e1}, ep1 = {e2, e3};
    rsp0 += ep0; rsp1 += ep1;
    f32x2 u0 = b0 + chm0, u1 = b1 + chm1;
    float f0 = __builtin_amdgcn_exp2f(u0.x), f1 = __builtin_amdgcn_exp2f(u0.y);
    float f2 = __builtin_amdgcn_exp2f(u1.x), f3 = __builtin_amdgcn_exp2f(u1.y);
    redC[(16 * c + m) * 33 + 4 * w + quad] = (f0 + f1) + (f2 + f3);
  }
  {
    int rbase = (16 * w + 4 * quad) * 17 + m;
    redR[rbase] = rsp0.x; redR[rbase + 17] = rsp0.y;
    redR[rbase + 34] = rsp1.x; redR[rbase + 51] = rsp1.y;
  }
  __syncthreads();   // #5

  if (t < 128) {
    float s = 0.f;
#pragma unroll
    for (int k = 0; k < 16; ++k) s += redR[t * 17 + k];
    A.prow[((size_t)b * NCHK + J) * NN + i0 + t] = make_float2(rowM[t], s);
  } else if (t < 256) {
    if (!(A.sym && I == J)) {   // diagonal col-dir duplicates row-dir: skip
      int cc = t - 128;
      float s = 0.f;
#pragma unroll
      for (int k = 0; k < 32; ++k) s += redC[cc * 33 + k];
      A.pcol[((size_t)b * NCHK + I) * NN + j0 + cc] = make_float2(colM[cc], s);
    }
  }
}

// ---------------------------------------------------------------------------
// merge 16 chunk-partials per row -> softmin + Jacobi update + next-h write.
// Partials in log2 domain: ft = -eps*ln2*(M + log2(S)).
// ---------------------------------------------------------------------------
struct MergeArgs {
  const float2* part;
  const float* fold;
  float* fout;
  const float* hbase;   // alog or blog (log2 domain)
  float* hout;          // h vector consumed by the next tile_fused
};

__global__ __launch_bounds__(256) void merge4(
    MergeArgs M0, MergeArgs M1, MergeArgs M2, MergeArgs M3,
    float eps, float alpha, float beta, float nextgs)
{
  MergeArgs A = (blockIdx.z == 0) ? M0 : (blockIdx.z == 1) ? M1
              : (blockIdx.z == 2) ? M2 : M3;
  const int b = blockIdx.y;
  const int i = blockIdx.x * 256 + threadIdx.x;   // grid.x = NN/256
  float2 p[NCHK];
#pragma unroll
  for (int k = 0; k < NCHK; ++k)
    p[k] = A.part[((size_t)b * NCHK + k) * NN + i];
  float M = p[0].x;
#pragma unroll
  for (int k = 1; k < NCHK; ++k) M = fmaxf(M, p[k].x);
  float S = 0.f;
#pragma unroll
  for (int k = 0; k < NCHK; ++k) S += p[k].y * __builtin_amdgcn_exp2f(p[k].x - M);
  float ft = (-LN2 * eps) * (M + __log2f(S));
  int idx = b * NN + i;
  float fnew = alpha * A.fold[idx] + beta * ft;
  A.fout[idx] = fnew;
  A.hout[idx] = fmaf(nextgs * L2E, fnew, A.hbase[idx]);
}

// ---------------------------------------------------------------------------
__global__ __launch_bounds__(256) void loss_kernel(
    const float* __restrict__ w1, const float* __restrict__ w2,
    float* __restrict__ out)
{
  __shared__ float red[256];
  float acc = 0.f;
  for (int idx = threadIdx.x; idx < NB * NN; idx += 256) {
    acc += w1[idx] * (g_fab[2][idx] - g_faa[2][idx])
         + w2[idx] * (g_gba[2][idx] - g_gbb[2][idx]);
  }
  red[threadIdx.x] = acc;
  __syncthreads();
  for (int s = 128; s > 0; s >>= 1) {
    if (threadIdx.x < s) red[threadIdx.x] += red[threadIdx.x + s];
    __syncthreads();
  }
  if (threadIdx.x == 0) out[0] = red[0] * (1.0f / NB);
}

// ---------------------------------------------------------------------------
extern "C" void kernel_launch(void* const* d_in, const int* in_sizes, int n_in,
                              void* d_out, int out_size, void* d_ws, size_t ws_size,
                              hipStream_t stream)
{
  const float* x = (const float*)d_in[0];
  const float* y = (const float*)d_in[1];
  const float* w1 = (const float*)d_in[2];
  const float* w2 = (const float*)d_in[3];
  float* out = (float*)d_out;

  half_t *xh, *yh;
  float *xn, *yn;
  float *h0, *h1, *h2, *h3, *fabp, *gbap, *faap, *gbbp, *alog, *blog;
  float2 *pfab, *pgba, *pfaa, *pgbb;
  hipGetSymbolAddress((void**)&xh, HIP_SYMBOL(g_xh));
  hipGetSymbolAddress((void**)&yh, HIP_SYMBOL(g_yh));
  hipGetSymbolAddress((void**)&xn, HIP_SYMBOL(g_xn));
  hipGetSymbolAddress((void**)&yn, HIP_SYMBOL(g_yn));
  hipGetSymbolAddress((void**)&h0, HIP_SYMBOL(g_h0));
  hipGetSymbolAddress((void**)&h1, HIP_SYMBOL(g_h1));
  hipGetSymbolAddress((void**)&h2, HIP_SYMBOL(g_h2));
  hipGetSymbolAddress((void**)&h3, HIP_SYMBOL(g_h3));
  hipGetSymbolAddress((void**)&fabp, HIP_SYMBOL(g_fab));
  hipGetSymbolAddress((void**)&gbap, HIP_SYMBOL(g_gba));
  hipGetSymbolAddress((void**)&faap, HIP_SYMBOL(g_faa));
  hipGetSymbolAddress((void**)&gbbp, HIP_SYMBOL(g_gbb));
  hipGetSymbolAddress((void**)&alog, HIP_SYMBOL(g_alog));
  hipGetSymbolAddress((void**)&blog, HIP_SYMBOL(g_blog));
  hipGetSymbolAddress((void**)&pfab, HIP_SYMBOL(g_pfab));
  hipGetSymbolAddress((void**)&pgba, HIP_SYMBOL(g_pgba));
  hipGetSymbolAddress((void**)&pfaa, HIP_SYMBOL(g_pfaa));
  hipGetSymbolAddress((void**)&pgbb, HIP_SYMBOL(g_pgbb));

  auto fab = [&](int s) { return fabp + (size_t)s * NB * NN; };
  auto gba = [&](int s) { return gbap + (size_t)s * NB * NN; };
  auto faa = [&](int s) { return faap + (size_t)s * NB * NN; };
  auto gbb = [&](int s) { return gbbp + (size_t)s * NB * NN; };

  // eps schedule (matches the Python double loop, then cast to fp32)
  float eps_list[32];
  int ne = 0;
  {
    double v = 64.0 * 64.0;
    double tgt = 0.05 * 0.05;
    while (v > tgt) { eps_list[ne++] = (float)v; v *= 0.25; }
    eps_list[ne++] = (float)tgt;   // ne == 12
  }

  prep_kernel<<<4096, 256, 0, stream>>>(x, y, w1, w2);

  dim3 tg(4224);                // flattened: 2048 xy + 1088 xx + 1088 yy
  dim3 mg(NN / 256, NB, 4);     // z: potential

  auto launch_iter = [&](float eps, float alpha, float beta, float nextgs,
                         int in, int outsel) {
    float keps = L2E / eps;
    FusedArgs T0 = {xh, yh, xn, yn, h0, h1, pfab, pgba, 0};
    FusedArgs T1 = {xh, xh, xn, xn, h2, h2, pfaa, pfaa, 1};
    FusedArgs T2 = {yh, yh, yn, yn, h3, h3, pgbb, pgbb, 1};
    tile_fused<<<tg, 512, 0, stream>>>(T0, T1, T2, keps);
    MergeArgs M0 = {pfab, fab(in), fab(outsel), alog, h1};
    MergeArgs M1 = {pgba, gba(in), gba(outsel), blog, h0};
    MergeArgs M2 = {pfaa, faa(in), faa(outsel), alog, h2};
    MergeArgs M3 = {pgbb, gbb(in), gbb(outsel), blog, h3};
    merge4<<<mg, 256, 0, stream>>>(M0, M1, M2, M3, eps, alpha, beta, nextgs);
  };

  // init at eps0: h = base log2-weights (gs=0), alpha=0 -> no carry read;
  // its merge writes h for scan step k=0.
  hprep_kernel<<<64, 256, 0, stream>>>(fab(0), gba(0), faa(0), gbb(0), 0.f);
  launch_iter(eps_list[0], 0.f, 1.f, 1.0f / eps_list[0], 0, 0);

  // scan over the full eps list with 0.5-averaging (Jacobi, banks 0/1);
  // each merge writes h for the NEXT step (k+1, or the final extrapolation).
  int cur = 0;
  for (int k = 0; k < ne; ++k) {
    int nxt = 1 - cur;
    float nextgs = 1.0f / ((k < ne - 1) ? eps_list[k + 1] : eps_list[ne - 1]);
    launch_iter(eps_list[k], 0.5f, 0.5f, nextgs, cur, nxt);
    cur = nxt;
  }

  // final extrapolation at eps = blur^p (no averaging) -> bank 2
  launch_iter(eps_list[ne - 1], 0.f, 1.f, 0.f, cur, 2);

  loss_kernel<<<1, 256, 0, stream>>>(w1, w2, out);
}